// Round 13
// baseline (208.445 us; speedup 1.0000x reference)
//
#include <hip/hip_runtime.h>
#include <math.h>

#define BS 8192
#define HALF 4096
#define DIM 1024
#define BIGP 1.0e10f
#define SQRT_TAU_INV 4.472135955f  // sqrt(20): prescale both operands -> acc = sim/tau

typedef __attribute__((ext_vector_type(8))) short bf16x8;
typedef __attribute__((ext_vector_type(4))) float f32x4;

#define GLOAD_LDS16(g, l)                                              \
    __builtin_amdgcn_global_load_lds(                                  \
        (const __attribute__((address_space(1))) void*)(g),            \
        (__attribute__((address_space(3))) void*)(l), 16, 0, 0)

__device__ inline unsigned short f2bf(float f) {
    union { float f; unsigned int u; } c; c.f = f;
    unsigned int u = c.u;
    u += 0x7FFFu + ((u >> 16) & 1u);
    return (unsigned short)(u >> 16);
}

// ---------------------------------------------------------------------------
// 1) Row-normalize concat(f1,f2), scale by sqrt(1/tau), convert to bf16.
// ---------------------------------------------------------------------------
__global__ __launch_bounds__(256) void norm_kernel(const float* __restrict__ f1,
                                                   const float* __restrict__ f2,
                                                   unsigned short* __restrict__ nb) {
    const int row = blockIdx.x;
    const int t = threadIdx.x;
    const float* src = (row < HALF) ? (f1 + (size_t)row * DIM)
                                    : (f2 + (size_t)(row - HALF) * DIM);
    float4 v = reinterpret_cast<const float4*>(src)[t];
    float ss = v.x * v.x + v.y * v.y + v.z * v.z + v.w * v.w;
#pragma unroll
    for (int off = 32; off > 0; off >>= 1) ss += __shfl_down(ss, off, 64);
    __shared__ float red[4];
    if ((t & 63) == 0) red[t >> 6] = ss;
    __syncthreads();
    float tot = red[0] + red[1] + red[2] + red[3];
    float inv = SQRT_TAU_INV / fmaxf(sqrtf(tot), 1e-8f);
    ushort4 o;
    o.x = f2bf(v.x * inv);
    o.y = f2bf(v.y * inv);
    o.z = f2bf(v.z * inv);
    o.w = f2bf(v.w * inv);
    reinterpret_cast<ushort4*>(nb + (size_t)row * DIM)[t] = o;
}

// ---------------------------------------------------------------------------
// 2) SYMMETRIC S/tau = N'*N'^T, upper-triangle blocks, column-major order.
//    K-loop: m97 structure (global_load_lds w16, both-sides XOR swizzle).
//    Epilogue: COALESCED LDS-staged streaming (theory: per-instruction
//    address scatter — 16 rows x 64B per store — caps effective HBM BW at
//    2.9 TB/s; streaming via LDS gives 512B-contiguous-per-32-lanes stores).
//    4 phases: h=0,1 direct halves (dump by wr), h=2,3 transposed halves
//    (dump by wc, swapped indices). Stream computes exp-sums inline with a
//    32-lane shfl reduce. psum: direct row-sums -> slot bx; transposed
//    col-sums -> slot 64+by. Exact partition at reduce: cols >= rb*128 from
//    direct slots bx>=rb, cols < rb*128 from transposed slots by<rb.
// ---------------------------------------------------------------------------
#define BM 128
#define BN 128
#define BK 64
#define TLD 133   // padded T row stride (floats): breaks 128-float bank cycle

__global__ __launch_bounds__(256) void gemm_kernel(const unsigned short* __restrict__ nb,
                                                   float* __restrict__ logits,
                                                   float* __restrict__ psum,
                                                   float* __restrict__ targ) {
    __shared__ union SM {
        struct { unsigned short A[BM][BK]; unsigned short B[BN][BK]; } s;  // 32 KB
        float T[64][TLD];                                                   // 34048 B
    } sm;

    const int t = threadIdx.x;
    const int lane = t & 63;
    const int wid = t >> 6;
    const int wr = wid >> 1;
    const int wc = wid & 1;
    const int lo = lane & 15;
    const int hi = lane >> 4;

    // triangular decode: column-major upper triangle, bx >= by
    const int id = blockIdx.x;
    int bx = (int)((sqrtf(8.0f * (float)id + 1.0f) - 1.0f) * 0.5f);
    while ((bx + 1) * (bx + 2) / 2 <= id) ++bx;
    while (bx * (bx + 1) / 2 > id) --bx;
    const int by = id - bx * (bx + 1) / 2;
    const bool diag = (bx == by);

    const int rowBase = by * BM;
    const int colBase = bx * BN;

    f32x4 acc[4][4];
#pragma unroll
    for (int m = 0; m < 4; ++m)
#pragma unroll
        for (int n = 0; n < 4; ++n) {
            acc[m][n][0] = 0.f; acc[m][n][1] = 0.f;
            acc[m][n][2] = 0.f; acc[m][n][3] = 0.f;
        }

    // staging: LDS(row, cb) holds global (row, cb ^ ((row&7)<<4)) [bytes]
    const int srow = lane >> 3;
    const int skoff = (((lane & 7) ^ srow) << 3);
    const char* Abase = (const char*)&sm.s.A[0][0];
    const char* Bbase = (const char*)&sm.s.B[0][0];
    const int rswz = (lo & 7) << 4;

    for (int kt = 0; kt < DIM; kt += BK) {
#pragma unroll
        for (int i = 0; i < 4; ++i) {
            const int chunk = wid * 4 + i;
            const int r = chunk * 8 + srow;
            const unsigned short* gA = nb + (size_t)(rowBase + r) * DIM + kt + skoff;
            GLOAD_LDS16(gA, (char*)&sm.s.A[0][0] + chunk * 1024);
            const unsigned short* gB = nb + (size_t)(colBase + r) * DIM + kt + skoff;
            GLOAD_LDS16(gB, (char*)&sm.s.B[0][0] + chunk * 1024);
        }
        __syncthreads();

#pragma unroll
        for (int ks = 0; ks < BK; ks += 32) {
            bf16x8 a[4], b[4];
#pragma unroll
            for (int m = 0; m < 4; ++m) {
                const int rr = wr * 64 + m * 16 + lo;
                a[m] = *reinterpret_cast<const bf16x8*>(
                    Abase + rr * 128 + ((ks * 2 + hi * 16) ^ rswz));
            }
#pragma unroll
            for (int n = 0; n < 4; ++n) {
                const int rr = wc * 64 + n * 16 + lo;
                b[n] = *reinterpret_cast<const bf16x8*>(
                    Bbase + rr * 128 + ((ks * 2 + hi * 16) ^ rswz));
            }
#pragma unroll
            for (int m = 0; m < 4; ++m)
#pragma unroll
                for (int n = 0; n < 4; ++n)
                    acc[m][n] = __builtin_amdgcn_mfma_f32_16x16x32_bf16(a[m], b[n], acc[m][n], 0, 0, 0);
        }
        __syncthreads();
    }

    // ---- diagonal mask in place ----
    if (diag) {
#pragma unroll
        for (int m = 0; m < 4; ++m) {
            const int lr0 = wr * 64 + m * 16 + hi * 4;
#pragma unroll
            for (int n = 0; n < 4; ++n) {
                const int lc = wc * 64 + n * 16 + lo;
#pragma unroll
                for (int r = 0; r < 4; ++r)
                    if (lr0 + r == lc) acc[m][n][r] -= BIGP;
            }
        }
    }

    // ---- epilogue: 4 LDS-staged coalesced streaming phases ----
    // C/D mapping: local col = wc*64+n*16+lo, local row = wr*64+m*16+hi*4+r.
#pragma unroll
    for (int h = 0; h < 4; ++h) {
        __syncthreads();           // previous phase's readers done
        if (h < 2) {
            if (wr == h) {         // dump rows h*64..h*64+63, all 128 cols
#pragma unroll
                for (int m = 0; m < 4; ++m)
#pragma unroll
                    for (int n = 0; n < 4; ++n)
#pragma unroll
                        for (int r = 0; r < 4; ++r)
                            sm.T[m * 16 + hi * 4 + r][wc * 64 + n * 16 + lo] = acc[m][n][r];
            }
        } else {
            if (wc == h - 2) {     // dump transposed: T[col-half][row]
#pragma unroll
                for (int m = 0; m < 4; ++m)
#pragma unroll
                    for (int n = 0; n < 4; ++n)
#pragma unroll
                        for (int r = 0; r < 4; ++r)
                            sm.T[n * 16 + lo][wr * 64 + m * 16 + hi * 4 + r] = acc[m][n][r];
            }
        }
        __syncthreads();           // T filled

        const bool tp = (h >= 2);
        if (tp && diag) continue;  // block-uniform: skip lower-triangle dup
        const int h2 = tp ? h - 2 : h;

#pragma unroll
        for (int sweep = 0; sweep < 8; ++sweep) {
            const int idx = sweep * 256 + t;
            const int rl = idx >> 5;       // local row in T (0..63)
            const int c4 = idx & 31;       // 16B chunk within row (0..31)
            const f32x4 w = *reinterpret_cast<const f32x4*>(&sm.T[rl][c4 * 4]);
            float es = __expf(w[0] - 20.f) + __expf(w[1] - 20.f)
                     + __expf(w[2] - 20.f) + __expf(w[3] - 20.f);
            es += __shfl_xor(es, 1, 64);
            es += __shfl_xor(es, 2, 64);
            es += __shfl_xor(es, 4, 64);
            es += __shfl_xor(es, 8, 64);
            es += __shfl_xor(es, 16, 64);  // full-row sum in each 32-lane group
            if (!tp) {
                const int row = rowBase + h2 * 64 + rl;
                const int gc0 = colBase + c4 * 4;
                *reinterpret_cast<f32x4*>(&logits[(size_t)row * BS + gc0]) = w;
#pragma unroll
                for (int q = 0; q < 4; ++q)
                    if (gc0 + q == row + HALF) { targ[row] = w[q]; targ[row + HALF] = w[q]; }
                if (c4 == 0) psum[(size_t)bx * BS + row] = es;
            } else {
                const int grow = colBase + h2 * 64 + rl;
                *reinterpret_cast<f32x4*>(&logits[(size_t)grow * BS + rowBase + c4 * 4]) = w;
                if (c4 == 0) psum[(size_t)(64 + by) * BS + grow] = es;
            }
        }
    }
}

// ---------------------------------------------------------------------------
// 3) Per-row LSE finish: exact-partition slot read — direct slots bx in
//    [rb,64) cover cols rb*128..8191; transposed slots 64+by, by in [0,rb)
//    cover cols 0..rb*128-1. Always 64 loads per row.
// ---------------------------------------------------------------------------
__global__ __launch_bounds__(256) void reduce_rows_kernel(const float* __restrict__ psum,
                                                          const float* __restrict__ targ,
                                                          const int* __restrict__ mask,
                                                          float* __restrict__ partials,
                                                          float* __restrict__ ytrue_out) {
    const int t = threadIdx.x;
    const int row = blockIdx.x * 256 + t;
    const int rb = row >> 7;

    float total = 0.f;
    for (int cb = rb; cb < 64; ++cb) total += psum[(size_t)cb * BS + row];
    for (int cb = 0; cb < rb; ++cb) total += psum[(size_t)(64 + cb) * BS + row];

    const float pe = -(targ[row] - 20.0f - logf(total));
    const float w = 1.0f - (float)mask[row & (HALF - 1)];
    ytrue_out[row] = (float)((row < HALF) ? row + HALF : row - HALF);

    float a = w * pe, b = w;
#pragma unroll
    for (int off = 32; off > 0; off >>= 1) {
        a += __shfl_down(a, off, 64);
        b += __shfl_down(b, off, 64);
    }
    __shared__ float ra[4], rb_[4];
    if ((t & 63) == 0) { ra[t >> 6] = a; rb_[t >> 6] = b; }
    __syncthreads();
    if (t == 0) {
        partials[blockIdx.x] = ra[0] + ra[1] + ra[2] + ra[3];
        partials[32 + blockIdx.x] = rb_[0] + rb_[1] + rb_[2] + rb_[3];
    }
}

__global__ void loss_kernel(const float* __restrict__ partials,
                            float* __restrict__ loss_out) {
    if (threadIdx.x == 0) {
        float A = 0.f, B = 0.f;
        for (int i = 0; i < 32; ++i) { A += partials[i]; B += partials[32 + i]; }
        loss_out[0] = A / B;
    }
}

// ---------------------------------------------------------------------------
extern "C" void kernel_launch(void* const* d_in, const int* in_sizes, int n_in,
                              void* d_out, int out_size, void* d_ws, size_t ws_size,
                              hipStream_t stream) {
    const float* f1 = (const float*)d_in[0];
    const float* f2 = (const float*)d_in[1];
    const int* mask = (const int*)d_in[2];
    float* out = (float*)d_out;

    unsigned short* nb = (unsigned short*)d_ws;                          // 16 MB
    float* psum = (float*)((char*)d_ws + (size_t)BS * DIM * 2);          // 4 MB (128 x 8192)
    float* targ = psum + (size_t)128 * BS;                               // 32 KB
    float* partials = targ + BS;                                         // 256 B
    float* logits = out + 1;
    float* ytrue_out = out + 1 + (size_t)BS * BS;

    norm_kernel<<<BS, 256, 0, stream>>>(f1, f2, nb);

    const int ntri = (BS / BM) * (BS / BM + 1) / 2;   // 2080
    gemm_kernel<<<ntri, 256, 0, stream>>>(nb, logits, psum, targ);

    reduce_rows_kernel<<<BS / 256, 256, 0, stream>>>(psum, targ, mask, partials, ytrue_out);
    loss_kernel<<<1, 64, 0, stream>>>(partials, out);
}

// Round 14
// 196.045 us; speedup vs baseline: 1.0632x; 1.0632x over previous
//
#include <hip/hip_runtime.h>
#include <math.h>

#define BS 8192
#define HALF 4096
#define DIM 1024
#define BIGP 1.0e10f
#define SQRT_TAU_INV 4.472135955f  // sqrt(20): prescale both operands -> acc = sim/tau
#define BK 64
#define NT (DIM / BK)              // 16 K-tiles

typedef __attribute__((ext_vector_type(8))) short bf16x8;
typedef __attribute__((ext_vector_type(4))) float f32x4;

#define GLOAD_LDS16(g, l)                                              \
    __builtin_amdgcn_global_load_lds(                                  \
        (const __attribute__((address_space(1))) void*)(g),            \
        (__attribute__((address_space(3))) void*)(l), 16, 0, 0)

__device__ inline unsigned short f2bf(float f) {
    union { float f; unsigned int u; } c; c.f = f;
    unsigned int u = c.u;
    u += 0x7FFFu + ((u >> 16) & 1u);
    return (unsigned short)(u >> 16);
}

// ---------------------------------------------------------------------------
// 1) Row-normalize concat(f1,f2), scale by sqrt(1/tau), convert to bf16.
// ---------------------------------------------------------------------------
__global__ __launch_bounds__(256) void norm_kernel(const float* __restrict__ f1,
                                                   const float* __restrict__ f2,
                                                   unsigned short* __restrict__ nb) {
    const int row = blockIdx.x;
    const int t = threadIdx.x;
    const float* src = (row < HALF) ? (f1 + (size_t)row * DIM)
                                    : (f2 + (size_t)(row - HALF) * DIM);
    float4 v = reinterpret_cast<const float4*>(src)[t];
    float ss = v.x * v.x + v.y * v.y + v.z * v.z + v.w * v.w;
#pragma unroll
    for (int off = 32; off > 0; off >>= 1) ss += __shfl_down(ss, off, 64);
    __shared__ float red[4];
    if ((t & 63) == 0) red[t >> 6] = ss;
    __syncthreads();
    float tot = red[0] + red[1] + red[2] + red[3];
    float inv = SQRT_TAU_INV / fmaxf(sqrtf(tot), 1e-8f);
    ushort4 o;
    o.x = f2bf(v.x * inv);
    o.y = f2bf(v.y * inv);
    o.z = f2bf(v.z * inv);
    o.w = f2bf(v.w * inv);
    reinterpret_cast<ushort4*>(nb + (size_t)row * DIM)[t] = o;
}

// ---------------------------------------------------------------------------
// 2) SYMMETRIC S/tau, upper-triangle over 32 col-panels of 256 (528 blocks),
//    512 threads = 8 waves (2 wave-rows x 4 wave-cols; per-wave out 128x64).
//    COUNTED-VMCNT double-buffered K-pipeline (T3/T4): prologue stages
//    tiles 0,1; each iter: vmcnt(8) [tile t's 8 loads retired, t+1's stay
//    in flight ACROSS the barrier] -> s_barrier -> 4 MFMA quadrant-phases
//    (setprio around MFMA cluster, T5) -> s_barrier -> stage tile t+2 into
//    the buffer just freed. Never drains vmcnt to 0 in steady state.
//    Raw s_barrier + asm memory fences (NOT __syncthreads: it re-drains).
//    LDS: 2 x (256x64 A + 256x64 B) bf16, linear, both-sides XOR swizzle
//    (round-3-verified involution). Epilogue: round-10 scheme at 8 waves.
// ---------------------------------------------------------------------------
__global__ __launch_bounds__(512, 2) void gemm_kernel(const unsigned short* __restrict__ nb,
                                                      float* __restrict__ logits,
                                                      float* __restrict__ psum,
                                                      float* __restrict__ targ) {
    __shared__ unsigned short As[2][256][BK];   // 64 KB
    __shared__ unsigned short Bs[2][256][BK];   // 64 KB

    const int t = threadIdx.x;
    const int lane = t & 63;
    const int wid = t >> 6;        // 0..7
    const int wr = wid >> 2;       // wave row 0..1 (128 rows each)
    const int wcn = wid & 3;       // wave col 0..3 (64 cols each)
    const int lo = lane & 15;
    const int hi = lane >> 4;

    // triangular decode over 32 panels: column-major, bx >= by
    const int id = blockIdx.x;
    int bx = (int)((sqrtf(8.0f * (float)id + 1.0f) - 1.0f) * 0.5f);
    while ((bx + 1) * (bx + 2) / 2 <= id) ++bx;
    while (bx * (bx + 1) / 2 > id) --bx;
    const int by = id - bx * (bx + 1) / 2;
    const bool diag = (bx == by);

    const int rowBase = by * 256;
    const int colBase = bx * 256;

    f32x4 acc[8][4];
#pragma unroll
    for (int m = 0; m < 8; ++m)
#pragma unroll
        for (int n = 0; n < 4; ++n) {
            acc[m][n][0] = 0.f; acc[m][n][1] = 0.f;
            acc[m][n][2] = 0.f; acc[m][n][3] = 0.f;
        }

    // staging: LDS(row, cb) holds global (row, cb ^ ((row&7)<<4)) [bytes]
    const int srow = lane >> 3;
    const int skoff = (((lane & 7) ^ srow) << 3);
    const int rswz = (lo & 7) << 4;

    // 8 gload_lds per wave per K-tile (4 A-chunks + 4 B-chunks of 1 KB)
#define STAGE(kti, b) do {                                                       \
    const int kt_ = (kti) * BK;                                                  \
    _Pragma("unroll")                                                            \
    for (int i_ = 0; i_ < 4; ++i_) {                                             \
        const int chunk_ = wid * 4 + i_;            /* 0..31, wave-uniform */    \
        const int r_ = chunk_ * 8 + srow;                                        \
        GLOAD_LDS16(nb + (size_t)(rowBase + r_) * DIM + kt_ + skoff,             \
                    (char*)&As[b][0][0] + chunk_ * 1024);                        \
        GLOAD_LDS16(nb + (size_t)(colBase + r_) * DIM + kt_ + skoff,             \
                    (char*)&Bs[b][0][0] + chunk_ * 1024);                        \
    } } while (0)

    // 64 MFMA per K-tile per wave, in 4 quadrant-phases of 16
#define COMPUTE(cur) do {                                                        \
    const char* Ab = (const char*)&As[cur][0][0];                                \
    const char* Bb = (const char*)&Bs[cur][0][0];                                \
    bf16x8 bf[4][2];                                                             \
    _Pragma("unroll")                                                            \
    for (int n_ = 0; n_ < 4; ++n_)                                               \
        _Pragma("unroll")                                                        \
        for (int k2 = 0; k2 < 2; ++k2)                                           \
            bf[n_][k2] = *reinterpret_cast<const bf16x8*>(                       \
                Bb + (wcn * 64 + n_ * 16 + lo) * 128 + ((k2 * 64 + hi * 16) ^ rswz)); \
    _Pragma("unroll")                                                            \
    for (int q_ = 0; q_ < 4; ++q_) {                                             \
        bf16x8 af[2][2];                                                         \
        _Pragma("unroll")                                                        \
        for (int mm = 0; mm < 2; ++mm)                                           \
            _Pragma("unroll")                                                    \
            for (int k2 = 0; k2 < 2; ++k2)                                       \
                af[mm][k2] = *reinterpret_cast<const bf16x8*>(                   \
                    Ab + (wr * 128 + (q_ * 2 + mm) * 16 + lo) * 128 +            \
                         ((k2 * 64 + hi * 16) ^ rswz));                          \
        __builtin_amdgcn_s_setprio(1);                                           \
        _Pragma("unroll")                                                        \
        for (int mm = 0; mm < 2; ++mm)                                           \
            _Pragma("unroll")                                                    \
            for (int n_ = 0; n_ < 4; ++n_)                                       \
                _Pragma("unroll")                                                \
                for (int k2 = 0; k2 < 2; ++k2)                                   \
                    acc[q_ * 2 + mm][n_] = __builtin_amdgcn_mfma_f32_16x16x32_bf16( \
                        af[mm][k2], bf[n_][k2], acc[q_ * 2 + mm][n_], 0, 0, 0);  \
        __builtin_amdgcn_s_setprio(0);                                           \
    } } while (0)

    // prologue: 2 tiles in flight (16 outstanding loads per wave)
    STAGE(0, 0);
    STAGE(1, 1);

    for (int kt = 0; kt < NT - 1; ++kt) {
        const int cur = kt & 1;
        // tile kt's 8 loads retired; tile kt+1's 8 stay in flight
        asm volatile("s_waitcnt vmcnt(8)" ::: "memory");
        __builtin_amdgcn_s_barrier();
        asm volatile("" ::: "memory");
        COMPUTE(cur);
        asm volatile("" ::: "memory");
        __builtin_amdgcn_s_barrier();   // all waves done reading buf[cur]
        asm volatile("" ::: "memory");
        if (kt + 2 < NT) STAGE(kt + 2, cur);
    }
    // final tile: only its own 8 loads outstanding
    asm volatile("s_waitcnt vmcnt(0)" ::: "memory");
    __builtin_amdgcn_s_barrier();
    asm volatile("" ::: "memory");
    COMPUTE((NT - 1) & 1);

    // ---- diagonal mask in place ----
    if (diag) {
#pragma unroll
        for (int m = 0; m < 8; ++m) {
            const int lr0 = wr * 128 + m * 16 + hi * 4;
#pragma unroll
            for (int n = 0; n < 4; ++n) {
                const int lc = wcn * 64 + n * 16 + lo;
#pragma unroll
                for (int r = 0; r < 4; ++r)
                    if (lr0 + r == lc) acc[m][n][r] -= BIGP;
            }
        }
    }

    // ---- direct scalar stores + exp row/col partials + targets ----
    float sums[32];
    float psn[4] = {0.f, 0.f, 0.f, 0.f};
#pragma unroll
    for (int p = 0; p < 32; ++p) sums[p] = 0.f;

#pragma unroll
    for (int m = 0; m < 8; ++m) {
        const int trow0 = rowBase + wr * 128 + m * 16 + hi * 4;
#pragma unroll
        for (int n = 0; n < 4; ++n) {
            const int col = colBase + wcn * 64 + n * 16 + lo;
#pragma unroll
            for (int r = 0; r < 4; ++r) {
                const int row = trow0 + r;
                const float v = acc[m][n][r];
                logits[(size_t)row * BS + col] = v;
                if (col == row + HALF) { targ[row] = v; targ[col] = v; }
                const float e = __expf(v - 20.0f);  // diag cell -> 0
                sums[m * 4 + r] += e;
                psn[n] += e;
            }
        }
    }

    // ---- transposed tile, register-direct f32x4 stores (non-diag) ----
    if (!diag) {
#pragma unroll
        for (int m = 0; m < 8; ++m) {
            const int trow0 = rowBase + wr * 128 + m * 16 + hi * 4;
#pragma unroll
            for (int n = 0; n < 4; ++n) {
                const int col = colBase + wcn * 64 + n * 16 + lo;
                *reinterpret_cast<f32x4*>(&logits[(size_t)col * BS + trow0]) = acc[m][n];
            }
        }
    }

    // ---- row-sum reduce (two groups of 16) -> psum slot 4*bx+wcn ----
    float sel0 = 0.f, sel1 = 0.f;
#pragma unroll
    for (int p = 0; p < 16; ++p) {
        float sv = sums[p];
        sv += __shfl_xor(sv, 1, 64);
        sv += __shfl_xor(sv, 2, 64);
        sv += __shfl_xor(sv, 4, 64);
        sv += __shfl_xor(sv, 8, 64);
        sel0 = (lo == p) ? sv : sel0;
    }
#pragma unroll
    for (int p = 0; p < 16; ++p) {
        float sv = sums[16 + p];
        sv += __shfl_xor(sv, 1, 64);
        sv += __shfl_xor(sv, 2, 64);
        sv += __shfl_xor(sv, 4, 64);
        sv += __shfl_xor(sv, 8, 64);
        sel1 = (lo == p) ? sv : sel1;
    }
    const int base_r = rowBase + wr * 128 + (lo >> 2) * 16 + hi * 4 + (lo & 3);
    psum[(size_t)(4 * bx + wcn) * BS + base_r] = sel0;          // m in [0,4)
    psum[(size_t)(4 * bx + wcn) * BS + base_r + 64] = sel1;     // m in [4,8)

    // ---- col-sum reduce over hi groups -> psum slot 128 + 2*by+wr ----
    if (!diag) {
#pragma unroll
        for (int n = 0; n < 4; ++n) {
            psn[n] += __shfl_xor(psn[n], 16, 64);
            psn[n] += __shfl_xor(psn[n], 32, 64);
        }
        const float cw = (hi == 0) ? psn[0] : (hi == 1) ? psn[1]
                       : (hi == 2) ? psn[2] : psn[3];
        psum[(size_t)(128 + 2 * by + wr) * BS + colBase + wcn * 64 + hi * 16 + lo] = cw;
    }
#undef STAGE
#undef COMPUTE
}

// ---------------------------------------------------------------------------
// 3) Per-row LSE finish. Exact partition for row r (panel rb = r>>8):
//    direct slots 4*bx+wcn for bx>=rb (s in [4rb,128)) cover cols >= ...
//    each col-panel bx once; transposed slots 128+2*by+wr for by<rb
//    (s in [0,2rb)) cover col-panels < rb. One writer per (slot,row).
// ---------------------------------------------------------------------------
__global__ __launch_bounds__(256) void reduce_rows_kernel(const float* __restrict__ psum,
                                                          const float* __restrict__ targ,
                                                          const int* __restrict__ mask,
                                                          float* __restrict__ partials,
                                                          float* __restrict__ ytrue_out) {
    const int t = threadIdx.x;
    const int row = blockIdx.x * 256 + t;
    const int rb = row >> 8;

    float total = 0.f;
    for (int s = 4 * rb; s < 128; ++s) total += psum[(size_t)s * BS + row];
    for (int s = 0; s < 2 * rb; ++s) total += psum[(size_t)(128 + s) * BS + row];

    const float pe = -(targ[row] - 20.0f - logf(total));
    const float w = 1.0f - (float)mask[row & (HALF - 1)];
    ytrue_out[row] = (float)((row < HALF) ? row + HALF : row - HALF);

    float a = w * pe, b = w;
#pragma unroll
    for (int off = 32; off > 0; off >>= 1) {
        a += __shfl_down(a, off, 64);
        b += __shfl_down(b, off, 64);
    }
    __shared__ float ra[4], rb_[4];
    if ((t & 63) == 0) { ra[t >> 6] = a; rb_[t >> 6] = b; }
    __syncthreads();
    if (t == 0) {
        partials[blockIdx.x] = ra[0] + ra[1] + ra[2] + ra[3];
        partials[32 + blockIdx.x] = rb_[0] + rb_[1] + rb_[2] + rb_[3];
    }
}

__global__ void loss_kernel(const float* __restrict__ partials,
                            float* __restrict__ loss_out) {
    if (threadIdx.x == 0) {
        float A = 0.f, B = 0.f;
        for (int i = 0; i < 32; ++i) { A += partials[i]; B += partials[32 + i]; }
        loss_out[0] = A / B;
    }
}

// ---------------------------------------------------------------------------
extern "C" void kernel_launch(void* const* d_in, const int* in_sizes, int n_in,
                              void* d_out, int out_size, void* d_ws, size_t ws_size,
                              hipStream_t stream) {
    const float* f1 = (const float*)d_in[0];
    const float* f2 = (const float*)d_in[1];
    const int* mask = (const int*)d_in[2];
    float* out = (float*)d_out;

    unsigned short* nb = (unsigned short*)d_ws;                          // 16 MB
    float* psum = (float*)((char*)d_ws + (size_t)BS * DIM * 2);          // 6 MB (192 x 8192)
    float* targ = psum + (size_t)192 * BS;                               // 32 KB
    float* partials = targ + BS;                                         // 256 B
    float* logits = out + 1;
    float* ytrue_out = out + 1 + (size_t)BS * BS;

    norm_kernel<<<BS, 256, 0, stream>>>(f1, f2, nb);

    const int ntri = 32 * 33 / 2;   // 528 blocks over 256-panels
    gemm_kernel<<<ntri, 512, 0, stream>>>(nb, logits, psum, targ);

    reduce_rows_kernel<<<BS / 256, 256, 0, stream>>>(psum, targ, mask, partials, ytrue_out);
    loss_kernel<<<1, 64, 0, stream>>>(partials, out);
}

// Round 15
// 190.679 us; speedup vs baseline: 1.0932x; 1.0281x over previous
//
#include <hip/hip_runtime.h>
#include <math.h>

#define BS 8192
#define HALF 4096
#define DIM 1024
#define BIGP 1.0e10f
#define SQRT_TAU_INV 4.472135955f  // sqrt(20): prescale both operands -> acc = sim/tau
#define BK 64
#define NT (DIM / BK)              // 16 K-tiles

typedef __attribute__((ext_vector_type(8))) short bf16x8;
typedef __attribute__((ext_vector_type(4))) float f32x4;

#define GLOAD_LDS16(g, l)                                              \
    __builtin_amdgcn_global_load_lds(                                  \
        (const __attribute__((address_space(1))) void*)(g),            \
        (__attribute__((address_space(3))) void*)(l), 16, 0, 0)

#define FENCE() asm volatile("" ::: "memory")

__device__ inline unsigned short f2bf(float f) {
    union { float f; unsigned int u; } c; c.f = f;
    unsigned int u = c.u;
    u += 0x7FFFu + ((u >> 16) & 1u);
    return (unsigned short)(u >> 16);
}

// ---------------------------------------------------------------------------
// 1) Row-normalize concat(f1,f2), scale by sqrt(1/tau), convert to bf16.
// ---------------------------------------------------------------------------
__global__ __launch_bounds__(256) void norm_kernel(const float* __restrict__ f1,
                                                   const float* __restrict__ f2,
                                                   unsigned short* __restrict__ nb) {
    const int row = blockIdx.x;
    const int t = threadIdx.x;
    const float* src = (row < HALF) ? (f1 + (size_t)row * DIM)
                                    : (f2 + (size_t)(row - HALF) * DIM);
    float4 v = reinterpret_cast<const float4*>(src)[t];
    float ss = v.x * v.x + v.y * v.y + v.z * v.z + v.w * v.w;
#pragma unroll
    for (int off = 32; off > 0; off >>= 1) ss += __shfl_down(ss, off, 64);
    __shared__ float red[4];
    if ((t & 63) == 0) red[t >> 6] = ss;
    __syncthreads();
    float tot = red[0] + red[1] + red[2] + red[3];
    float inv = SQRT_TAU_INV / fmaxf(sqrtf(tot), 1e-8f);
    ushort4 o;
    o.x = f2bf(v.x * inv);
    o.y = f2bf(v.y * inv);
    o.z = f2bf(v.z * inv);
    o.w = f2bf(v.w * inv);
    reinterpret_cast<ushort4*>(nb + (size_t)row * DIM)[t] = o;
}

// ---------------------------------------------------------------------------
// 2) SYMMETRIC S/tau, upper-triangle over 32 col-panels of 256 (528 blocks),
//    512 threads = 8 waves (2Mx4N; per-wave out 128x64). m201-style 8-PHASE
//    K-pipeline, 2 K-tiles (a=buf0, b=buf1) per iter. Per phase:
//      ds_read quadrant frags -> 1 half-tile stage -> [vmcnt(4) at ph4/ph8]
//      -> barrier -> setprio(1) -> 16 MFMA -> setprio(0) -> barrier.
//    Stage placement (last-reader-safe, 1 barrier min separation):
//      ph1: A0(b)  ph2: A1(b)  ph3: B0(a+2)  ph4: B1(a+2)
//      ph5: A0(a+2) ph6: A1(a+2) ph7: B0(b+2) ph8: B1(b+2)
//    FIFO proof: @ph4 vmcnt(4) retires {B0,B1(b),A0,A1(b)} (read ph5-8),
//    leaves {B(a+2)} in flight; @ph8 vmcnt(4) retires {B(a+2),A(a+2)}
//    (read next ph1-4), leaves {B(b+2)}. Never drains to 0 mid-loop.
//    Final iter: skip stages of tiles >= NT, vmcnt(0) at ph4.
//    Epilogue: round-14 verified scheme (192-slot psum, barrier-free).
// ---------------------------------------------------------------------------
__global__ __launch_bounds__(512) void gemm_kernel(const unsigned short* __restrict__ nb,
                                                   float* __restrict__ logits,
                                                   float* __restrict__ psum,
                                                   float* __restrict__ targ) {
    __shared__ unsigned short As[2][256][BK];   // 64 KB
    __shared__ unsigned short Bs[2][256][BK];   // 64 KB

    const int t = threadIdx.x;
    const int lane = t & 63;
    const int wid = t >> 6;        // 0..7
    const int wr = wid >> 2;       // wave row 0..1 (128 rows each)
    const int wcn = wid & 3;       // wave col 0..3 (64 cols each)
    const int lo = lane & 15;
    const int hi = lane >> 4;

    // triangular decode over 32 panels: column-major, bx >= by
    const int id = blockIdx.x;
    int bx = (int)((sqrtf(8.0f * (float)id + 1.0f) - 1.0f) * 0.5f);
    while ((bx + 1) * (bx + 2) / 2 <= id) ++bx;
    while (bx * (bx + 1) / 2 > id) --bx;
    const int by = id - bx * (bx + 1) / 2;
    const bool diag = (bx == by);

    const int rowBase = by * 256;
    const int colBase = bx * 256;

    f32x4 acc[8][4];
#pragma unroll
    for (int m = 0; m < 8; ++m)
#pragma unroll
        for (int n = 0; n < 4; ++n) {
            acc[m][n][0] = 0.f; acc[m][n][1] = 0.f;
            acc[m][n][2] = 0.f; acc[m][n][3] = 0.f;
        }

    // staging: LDS(row, cb) holds global (row, cb ^ ((row&7)<<4)) [bytes]
    const int srow = lane >> 3;                      // row within 8-row chunk
    const int skoff = (((lane & 7) ^ srow) << 3);    // swizzled source col
    const int rswz = (lo & 7) << 4;                  // read-side XOR (bytes)

    // stage one half-tile (128 rows x BK) = 2 gload_lds/thread, wave-uniform dest
#define STAGE_HALF(tile, baseRow, half, dstbase) do {                          \
    const int kt_ = (tile) * BK;                                               \
    _Pragma("unroll")                                                          \
    for (int c_ = 0; c_ < 2; ++c_) {                                           \
        const int r_ = (half) * 128 + c_ * 64 + wid * 8 + srow;                \
        GLOAD_LDS16(nb + (size_t)((baseRow) + r_) * DIM + kt_ + skoff,         \
                    (char*)(dstbase) + (size_t)(half) * 16384 + c_ * 8192 + wid * 1024); \
    } } while (0)

#define LOAD_BF(bf, Bb) do {                                                   \
    _Pragma("unroll")                                                          \
    for (int n_ = 0; n_ < 4; ++n_)                                             \
        _Pragma("unroll")                                                      \
        for (int k2 = 0; k2 < 2; ++k2)                                         \
            bf[n_][k2] = *reinterpret_cast<const bf16x8*>(                     \
                (const char*)(Bb) + (wcn * 64 + n_ * 16 + lo) * 128 +          \
                ((k2 * 64 + hi * 16) ^ rswz));                                 \
    } while (0)

#define LOAD_AF(af, Ab, q) do {                                                \
    _Pragma("unroll")                                                          \
    for (int mm = 0; mm < 2; ++mm)                                             \
        _Pragma("unroll")                                                      \
        for (int k2 = 0; k2 < 2; ++k2)                                         \
            af[mm][k2] = *reinterpret_cast<const bf16x8*>(                     \
                (const char*)(Ab) + (wr * 128 + ((q) * 2 + mm) * 16 + lo) * 128 + \
                ((k2 * 64 + hi * 16) ^ rswz));                                 \
    } while (0)

#define MFMA16(af, bf, q) do {                                                 \
    __builtin_amdgcn_s_setprio(1);                                             \
    _Pragma("unroll")                                                          \
    for (int mm = 0; mm < 2; ++mm)                                             \
        _Pragma("unroll")                                                      \
        for (int n_ = 0; n_ < 4; ++n_)                                         \
            _Pragma("unroll")                                                  \
            for (int k2 = 0; k2 < 2; ++k2)                                     \
                acc[(q) * 2 + mm][n_] = __builtin_amdgcn_mfma_f32_16x16x32_bf16( \
                    af[mm][k2], bf[n_][k2], acc[(q) * 2 + mm][n_], 0, 0, 0);   \
    __builtin_amdgcn_s_setprio(0);                                             \
    } while (0)

#define BARRIER() do { FENCE(); __builtin_amdgcn_s_barrier(); FENCE(); } while (0)

    // ---- prologue: tile 0 (A+B -> buf0) then B(1) -> buf1; retire tile 0 ----
    STAGE_HALF(0, rowBase, 0, &As[0][0][0]);
    STAGE_HALF(0, rowBase, 1, &As[0][0][0]);
    STAGE_HALF(0, colBase, 0, &Bs[0][0][0]);
    STAGE_HALF(0, colBase, 1, &Bs[0][0][0]);
    STAGE_HALF(1, colBase, 0, &Bs[1][0][0]);
    STAGE_HALF(1, colBase, 1, &Bs[1][0][0]);
    asm volatile("s_waitcnt vmcnt(4)" ::: "memory");
    BARRIER();

    for (int i = 0; i < NT / 2; ++i) {
        const int a = 2 * i, b = 2 * i + 1;
        const bool last = (i == NT / 2 - 1);

        // ---- phases 1-4: tile a (buf0) ----
        {
            bf16x8 bf[4][2];
#pragma unroll
            for (int q = 0; q < 4; ++q) {
                if (q == 0) LOAD_BF(bf, &Bs[0][0][0]);
                bf16x8 af[2][2];
                LOAD_AF(af, &As[0][0][0], q);
                if (q == 0) STAGE_HALF(b, rowBase, 0, &As[1][0][0]);
                else if (q == 1) STAGE_HALF(b, rowBase, 1, &As[1][0][0]);
                else if (q == 2) { if (!last) STAGE_HALF(a + 2, colBase, 0, &Bs[0][0][0]); }
                else {
                    if (!last) {
                        STAGE_HALF(a + 2, colBase, 1, &Bs[0][0][0]);
                        asm volatile("s_waitcnt vmcnt(4)" ::: "memory");
                    } else {
                        asm volatile("s_waitcnt vmcnt(0)" ::: "memory");
                    }
                }
                BARRIER();
                MFMA16(af, bf, q);
                BARRIER();
            }
        }
        // ---- phases 5-8: tile b (buf1) ----
        {
            bf16x8 bf[4][2];
#pragma unroll
            for (int q = 0; q < 4; ++q) {
                if (q == 0) LOAD_BF(bf, &Bs[1][0][0]);
                bf16x8 af[2][2];
                LOAD_AF(af, &As[1][0][0], q);
                if (q == 0) { if (!last) STAGE_HALF(a + 2, rowBase, 0, &As[0][0][0]); }
                else if (q == 1) { if (!last) STAGE_HALF(a + 2, rowBase, 1, &As[0][0][0]); }
                else if (q == 2) { if (!last) STAGE_HALF(b + 2, colBase, 0, &Bs[1][0][0]); }
                else {
                    if (!last) {
                        STAGE_HALF(b + 2, colBase, 1, &Bs[1][0][0]);
                        asm volatile("s_waitcnt vmcnt(4)" ::: "memory");
                    }
                }
                BARRIER();
                MFMA16(af, bf, q);
                BARRIER();
            }
        }
    }

    // ---- diagonal mask in place ----
    if (diag) {
#pragma unroll
        for (int m = 0; m < 8; ++m) {
            const int lr0 = wr * 128 + m * 16 + hi * 4;
#pragma unroll
            for (int n = 0; n < 4; ++n) {
                const int lc = wcn * 64 + n * 16 + lo;
#pragma unroll
                for (int r = 0; r < 4; ++r)
                    if (lr0 + r == lc) acc[m][n][r] -= BIGP;
            }
        }
    }

    // ---- direct scalar stores + exp row/col partials + targets ----
    float sums[32];
    float psn[4] = {0.f, 0.f, 0.f, 0.f};
#pragma unroll
    for (int p = 0; p < 32; ++p) sums[p] = 0.f;

#pragma unroll
    for (int m = 0; m < 8; ++m) {
        const int trow0 = rowBase + wr * 128 + m * 16 + hi * 4;
#pragma unroll
        for (int n = 0; n < 4; ++n) {
            const int col = colBase + wcn * 64 + n * 16 + lo;
#pragma unroll
            for (int r = 0; r < 4; ++r) {
                const int row = trow0 + r;
                const float v = acc[m][n][r];
                logits[(size_t)row * BS + col] = v;
                if (col == row + HALF) { targ[row] = v; targ[col] = v; }
                const float e = __expf(v - 20.0f);  // diag cell -> 0
                sums[m * 4 + r] += e;
                psn[n] += e;
            }
        }
    }

    // ---- transposed tile, register-direct f32x4 stores (non-diag) ----
    if (!diag) {
#pragma unroll
        for (int m = 0; m < 8; ++m) {
            const int trow0 = rowBase + wr * 128 + m * 16 + hi * 4;
#pragma unroll
            for (int n = 0; n < 4; ++n) {
                const int col = colBase + wcn * 64 + n * 16 + lo;
                *reinterpret_cast<f32x4*>(&logits[(size_t)col * BS + trow0]) = acc[m][n];
            }
        }
    }

    // ---- row-sum reduce (two groups of 16) -> psum slot 4*bx+wcn ----
    float sel0 = 0.f, sel1 = 0.f;
#pragma unroll
    for (int p = 0; p < 16; ++p) {
        float sv = sums[p];
        sv += __shfl_xor(sv, 1, 64);
        sv += __shfl_xor(sv, 2, 64);
        sv += __shfl_xor(sv, 4, 64);
        sv += __shfl_xor(sv, 8, 64);
        sel0 = (lo == p) ? sv : sel0;
    }
#pragma unroll
    for (int p = 0; p < 16; ++p) {
        float sv = sums[16 + p];
        sv += __shfl_xor(sv, 1, 64);
        sv += __shfl_xor(sv, 2, 64);
        sv += __shfl_xor(sv, 4, 64);
        sv += __shfl_xor(sv, 8, 64);
        sel1 = (lo == p) ? sv : sel1;
    }
    const int base_r = rowBase + wr * 128 + (lo >> 2) * 16 + hi * 4 + (lo & 3);
    psum[(size_t)(4 * bx + wcn) * BS + base_r] = sel0;          // m in [0,4)
    psum[(size_t)(4 * bx + wcn) * BS + base_r + 64] = sel1;     // m in [4,8)

    // ---- col-sum reduce over hi groups -> psum slot 128 + 2*by+wr ----
    if (!diag) {
#pragma unroll
        for (int n = 0; n < 4; ++n) {
            psn[n] += __shfl_xor(psn[n], 16, 64);
            psn[n] += __shfl_xor(psn[n], 32, 64);
        }
        const float cw = (hi == 0) ? psn[0] : (hi == 1) ? psn[1]
                       : (hi == 2) ? psn[2] : psn[3];
        psum[(size_t)(128 + 2 * by + wr) * BS + colBase + wcn * 64 + hi * 16 + lo] = cw;
    }
#undef STAGE_HALF
#undef LOAD_BF
#undef LOAD_AF
#undef MFMA16
#undef BARRIER
}

// ---------------------------------------------------------------------------
// 3) Per-row LSE finish. Exact partition for row r (panel rb = r>>8):
//    direct slots s in [4rb,128) + transposed slots 128+s, s in [0,2rb).
// ---------------------------------------------------------------------------
__global__ __launch_bounds__(256) void reduce_rows_kernel(const float* __restrict__ psum,
                                                          const float* __restrict__ targ,
                                                          const int* __restrict__ mask,
                                                          float* __restrict__ partials,
                                                          float* __restrict__ ytrue_out) {
    const int t = threadIdx.x;
    const int row = blockIdx.x * 256 + t;
    const int rb = row >> 8;

    float total = 0.f;
    for (int s = 4 * rb; s < 128; ++s) total += psum[(size_t)s * BS + row];
    for (int s = 0; s < 2 * rb; ++s) total += psum[(size_t)(128 + s) * BS + row];

    const float pe = -(targ[row] - 20.0f - logf(total));
    const float w = 1.0f - (float)mask[row & (HALF - 1)];
    ytrue_out[row] = (float)((row < HALF) ? row + HALF : row - HALF);

    float a = w * pe, b = w;
#pragma unroll
    for (int off = 32; off > 0; off >>= 1) {
        a += __shfl_down(a, off, 64);
        b += __shfl_down(b, off, 64);
    }
    __shared__ float ra[4], rb_[4];
    if ((t & 63) == 0) { ra[t >> 6] = a; rb_[t >> 6] = b; }
    __syncthreads();
    if (t == 0) {
        partials[blockIdx.x] = ra[0] + ra[1] + ra[2] + ra[3];
        partials[32 + blockIdx.x] = rb_[0] + rb_[1] + rb_[2] + rb_[3];
    }
}

__global__ void loss_kernel(const float* __restrict__ partials,
                            float* __restrict__ loss_out) {
    if (threadIdx.x == 0) {
        float A = 0.f, B = 0.f;
        for (int i = 0; i < 32; ++i) { A += partials[i]; B += partials[32 + i]; }
        loss_out[0] = A / B;
    }
}

// ---------------------------------------------------------------------------
extern "C" void kernel_launch(void* const* d_in, const int* in_sizes, int n_in,
                              void* d_out, int out_size, void* d_ws, size_t ws_size,
                              hipStream_t stream) {
    const float* f1 = (const float*)d_in[0];
    const float* f2 = (const float*)d_in[1];
    const int* mask = (const int*)d_in[2];
    float* out = (float*)d_out;

    unsigned short* nb = (unsigned short*)d_ws;                          // 16 MB
    float* psum = (float*)((char*)d_ws + (size_t)BS * DIM * 2);          // 6 MB (192 x 8192)
    float* targ = psum + (size_t)192 * BS;                               // 32 KB
    float* partials = targ + BS;                                         // 256 B
    float* logits = out + 1;
    float* ytrue_out = out + 1 + (size_t)BS * BS;

    norm_kernel<<<BS, 256, 0, stream>>>(f1, f2, nb);

    const int ntri = 32 * 33 / 2;   // 528 blocks over 256-panels
    gemm_kernel<<<ntri, 512, 0, stream>>>(nb, logits, psum, targ);

    reduce_rows_kernel<<<BS / 256, 256, 0, stream>>>(psum, targ, mask, partials, ytrue_out);
    loss_kernel<<<1, 64, 0, stream>>>(partials, out);
}